// Round 6
// baseline (130.427 us; speedup 1.0000x reference)
//
#include <hip/hip_runtime.h>
#include <stdint.h>

#define UNITS 1024
#define BATCH 4096
#define FOURU 4096

typedef __bf16 bf16x8 __attribute__((ext_vector_type(8)));
typedef float f32x4 __attribute__((ext_vector_type(4)));

// counted vmcnt wait (memory clobber: no memory op may cross)
#define VMW(n) asm volatile("s_waitcnt vmcnt(" #n ")" ::: "memory")

// round-to-nearest-even f32 -> bf16
__device__ __forceinline__ uint16_t f2bf(float f) {
  uint32_t u = __builtin_bit_cast(uint32_t, f);
  u += 0x7FFFu + ((u >> 16) & 1u);
  return (uint16_t)(u >> 16);
}
__device__ __forceinline__ float bf2f(uint16_t b) {
  uint32_t u = ((uint32_t)b) << 16;
  return __builtin_bit_cast(float, u);
}
__device__ __forceinline__ float fsig(float x) {
  return 1.0f / (1.0f + __expf(-x));
}
__device__ __forceinline__ f32x4 mfma16x16x32(bf16x8 a, bf16x8 b, f32x4 c) {
  return __builtin_amdgcn_mfma_f32_16x16x32_bf16(a, b, c, 0, 0, 0);
}

// async global->LDS, 16B per lane; LDS dest must be wave-uniform (+lane*16 HW)
__device__ __forceinline__ void gll16(uint16_t* lds, const uint16_t* g) {
  __builtin_amdgcn_global_load_lds(
      (const __attribute__((address_space(1))) uint32_t*)g,
      (__attribute__((address_space(3))) uint32_t*)lds, 16, 0, 0);
}

// Granule swizzle (BK=32 tile = [ROWS][4 granules of 8 bf16]); stored granule
// (row,s) holds global (row, kg = s ^ ((row>>1)&3)). gload_lds dest LINEAR;
// permutation lives in per-lane GLOBAL source. Verified: conflicts 2.1M -> 0.
__device__ __forceinline__ int fidx(int row, int l4) {
  return row * 4 + (l4 ^ ((row >> 1) & 3));
}

template <int ROWS>
__device__ __forceinline__ void stage32s(const uint16_t* __restrict__ src,
                                         uint16_t* lds, int tid) {
  const int wb = tid & 192;  // wave*64 granules
#pragma unroll
  for (int p = 0; p < ROWS / 64; ++p) {
    const int gi = p * 256 + tid;
    const int row = gi >> 2;
    const int kg = (gi & 3) ^ ((row >> 1) & 3);
    gll16(lds + (p * 256 + wb) * 8, src + row * UNITS + kg * 8);
  }
}

// ---- prep (fused): blocks [0,4096): h f32->bf16; [4096,8192): R -> RT bf16 ----
__global__ __launch_bounds__(256) void prep_kernel(const float* __restrict__ h32,
                                                   uint16_t* __restrict__ hbf,
                                                   const float* __restrict__ R,
                                                   uint16_t* __restrict__ RT) {
  __shared__ float t[32][33];
  const int b = blockIdx.x;
  if (b < 4096) {
    const int i = (b * 256 + threadIdx.x) * 4;
    float4 v = *(const float4*)(h32 + i);
    ushort4 o;
    o.x = f2bf(v.x); o.y = f2bf(v.y); o.z = f2bf(v.z); o.w = f2bf(v.w);
    *(ushort4*)(hbf + i) = o;
  } else {
    const int bb = b - 4096;
    const int n0 = (bb & 127) * 32, k0 = (bb >> 7) * 32;
    const int tx = threadIdx.x & 31, ty = threadIdx.x >> 5;
#pragma unroll
    for (int i = 0; i < 4; ++i)
      t[ty + i * 8][tx] = R[(size_t)(k0 + ty + i * 8) * FOURU + n0 + tx];
    __syncthreads();
#pragma unroll
    for (int i = 0; i < 4; ++i)
      RT[(size_t)(n0 + ty + i * 8) * UNITS + k0 + tx] = f2bf(t[tx][ty + i * 8]);
  }
}

// ---- unified GEMM: BM=64, BN=128, BK=32, 4 waves of 32x64 (acc 2x4).
// 4-buffer LDS, 3 stages in flight, COUNTED vmcnt (T3+T4: never drain to 0
// in main loop), one raw barrier per K-step.
// Per-thread loads/stage L=3 (A:1, B:2) -> steady-state wait vmcnt(2L)=6.
// EPI 0: s1 (z cols [0,1024), r cols [1024,2048)) -> zb(bf16) / rhb(bf16)
// EPI 1: s2: hh=tanh(+ch+b1); hn=z*h+(1-z)*hh -> h_out(f32) + hnb(bf16)
// EPI 2: s3: o =tanh(+co+b2) -> o_out(f32)
template <int EPI>
__global__ __launch_bounds__(256, 3) void gemm_kernel(
    const uint16_t* __restrict__ abf, const uint16_t* __restrict__ bt,
    const int* __restrict__ idx, const float* __restrict__ kc,
    const float* __restrict__ bz, const float* __restrict__ bias,
    const uint16_t* __restrict__ hbf, const uint16_t* __restrict__ zb_in,
    float* __restrict__ out32, uint16_t* __restrict__ outbf,
    uint16_t* __restrict__ out2bf) {
  __shared__ uint16_t sA[4][64 * 32];    // 16 KB
  __shared__ uint16_t sB[4][128 * 32];   // 32 KB
  const int tid = threadIdx.x;
  const int lane = tid & 63, wave = tid >> 6;
  const int l15 = lane & 15, l4 = lane >> 4;
  // T1 bijective XCD swizzle (nwg divisible by 8); M/BM = 64 rows always.
  const int fid = blockIdx.y * gridDim.x + blockIdx.x;
  const int q = (gridDim.x * gridDim.y) >> 3;
  const int nid = (fid & 7) * q + (fid >> 3);
  const int row0 = (nid & 63) * 64;
  const int col0 = (nid >> 6) * 128;
  const int wr = wave >> 1, wc = wave & 1;
  const uint16_t* pa = abf + (size_t)row0 * UNITS;
  const uint16_t* pb = bt + (size_t)col0 * UNITS;
  f32x4 acc[2][4] = {};

  auto stageAB = [&](int t) {
    stage32s<64>(pa + t * 32, sA[t & 3], tid);
    stage32s<128>(pb + t * 32, sB[t & 3], tid);
  };
  auto consume = [&](int b) {
    const bf16x8* A8 = (const bf16x8*)sA[b];
    const bf16x8* B8 = (const bf16x8*)sB[b];
    bf16x8 af[2], bfr[4];
#pragma unroll
    for (int m = 0; m < 2; ++m) af[m] = A8[fidx(wr * 32 + m * 16 + l15, l4)];
#pragma unroll
    for (int n = 0; n < 4; ++n) bfr[n] = B8[fidx(wc * 64 + n * 16 + l15, l4)];
#pragma unroll
    for (int m = 0; m < 2; ++m)
#pragma unroll
      for (int n = 0; n < 4; ++n)
        acc[m][n] = mfma16x16x32(af[m], bfr[n], acc[m][n]);
  };

  // prologue: 3 stages in flight (9 loads/thread)
  stageAB(0);
  stageAB(1);
  stageAB(2);

  // main loop: t = 0..28, stage t+3 each step, never drain vmcnt to 0
  for (int t = 0; t < 29; ++t) {
    VMW(6);  // own buf[t] loads done (bufs t+1,t+2 = 6 loads may remain)
    __builtin_amdgcn_s_barrier();  // all waves' buf[t] loads landed; all waves
                                   // retired reads of buf[(t+3)&3] (t-1 step)
    __builtin_amdgcn_sched_barrier(0);
    stageAB(t + 3);
    consume(t & 3);
  }
  // tail: t = 29,30,31 (no more stages; outstanding shrinks 9->6->3->0)
  VMW(6);
  __builtin_amdgcn_s_barrier();
  __builtin_amdgcn_sched_barrier(0);
  consume(1);
  VMW(3);
  __builtin_amdgcn_s_barrier();
  __builtin_amdgcn_sched_barrier(0);
  consume(2);
  VMW(0);
  __builtin_amdgcn_s_barrier();
  __builtin_amdgcn_sched_barrier(0);
  consume(3);

  const bool is_z = (col0 < UNITS);  // block-uniform (EPI 0 only)
#pragma unroll
  for (int m = 0; m < 2; ++m) {
#pragma unroll
    for (int qq = 0; qq < 4; ++qq) {
      const int i = row0 + wr * 32 + m * 16 + l4 * 4 + qq;
      const int ch = idx[i];
      const float* kcrow = kc + (size_t)ch * FOURU;
#pragma unroll
      for (int n = 0; n < 4; ++n) {
        const int jc = col0 + wc * 64 + n * 16 + l15;
        const float a = acc[m][n][qq];
        if (EPI == 0) {
          if (is_z) {
            float z = fsig(a + kcrow[jc] + bz[jc]);
            outbf[(size_t)i * UNITS + jc] = f2bf(z);
          } else {
            const int j = jc - UNITS;
            const size_t ij = (size_t)i * UNITS + j;
            float r = fsig(a + kcrow[jc] + bias[j]);
            out2bf[ij] = f2bf(r * bf2f(hbf[ij]));
          }
        } else if (EPI == 1) {
          const size_t ij = (size_t)i * UNITS + jc;
          float hh = tanhf(a + kcrow[2 * UNITS + jc] + bias[UNITS + jc]);
          float z = bf2f(zb_in[ij]);
          float hv = bf2f(hbf[ij]);
          float hn = z * hv + (1.0f - z) * hh;
          out32[ij] = hn;
          outbf[ij] = f2bf(hn);
        } else {
          const size_t ij = (size_t)i * UNITS + jc;
          out32[ij] = tanhf(a + kcrow[3 * UNITS + jc] + bias[2 * UNITS + jc]);
        }
      }
    }
  }
}

extern "C" void kernel_launch(void* const* d_in, const int* in_sizes, int n_in,
                              void* d_out, int out_size, void* d_ws, size_t ws_size,
                              hipStream_t stream) {
  const int* idx = (const int*)d_in[0];
  const float* h32 = (const float*)d_in[1];
  const float* R = (const float*)d_in[2];
  const float* kc = (const float*)d_in[3];
  const float* bz = (const float*)d_in[4];
  const float* bias = (const float*)d_in[5];

  float* o_out = (float*)d_out;                  // 4M f32 (output o)
  float* h_out = o_out + (size_t)BATCH * UNITS;  // 4M f32 (output h)

  uint16_t* hbf = (uint16_t*)d_ws;               // bf16(h_tm1)   8 MB
  uint16_t* rt = hbf + (size_t)BATCH * UNITS;    // bf16(R^T)     8 MB
  uint16_t* rhb = rt + (size_t)FOURU * UNITS;    // bf16(r*h)     8 MB
  uint16_t* hnb = rhb + (size_t)BATCH * UNITS;   // bf16(h_new)   8 MB
  uint16_t* zbuf = hnb + (size_t)BATCH * UNITS;  // bf16(z)       8 MB

  prep_kernel<<<dim3(8192), 256, 0, stream>>>(h32, hbf, R, rt);

  // s1: N=2048 z|r GEMM -> grid (16,64)=1024 blocks
  gemm_kernel<0><<<dim3(16, 64), 256, 0, stream>>>(
      hbf, rt, idx, kc, bz, bias, hbf, nullptr, nullptr, zbuf, rhb);

  // s2: N=1024 -> grid (8,64)=512 blocks
  gemm_kernel<1><<<dim3(8, 64), 256, 0, stream>>>(
      rhb, rt + (size_t)2 * UNITS * UNITS, idx, kc, bz, bias, hbf, zbuf,
      h_out, hnb, nullptr);

  // s3: N=1024 -> grid (8,64)=512 blocks
  gemm_kernel<2><<<dim3(8, 64), 256, 0, stream>>>(
      hnb, rt + (size_t)3 * UNITS * UNITS, idx, kc, bz, bias, nullptr, nullptr,
      o_out, nullptr, nullptr);
}

// Round 7
// 110.171 us; speedup vs baseline: 1.1839x; 1.1839x over previous
//
#include <hip/hip_runtime.h>
#include <stdint.h>

#define UNITS 1024
#define BATCH 4096
#define FOURU 4096

typedef __bf16 bf16x8 __attribute__((ext_vector_type(8)));
typedef float f32x4 __attribute__((ext_vector_type(4)));

// round-to-nearest-even f32 -> bf16
__device__ __forceinline__ uint16_t f2bf(float f) {
  uint32_t u = __builtin_bit_cast(uint32_t, f);
  u += 0x7FFFu + ((u >> 16) & 1u);
  return (uint16_t)(u >> 16);
}
__device__ __forceinline__ float bf2f(uint16_t b) {
  uint32_t u = ((uint32_t)b) << 16;
  return __builtin_bit_cast(float, u);
}
__device__ __forceinline__ float fsig(float x) {
  return 1.0f / (1.0f + __expf(-x));
}
__device__ __forceinline__ f32x4 mfma16x16x32(bf16x8 a, bf16x8 b, f32x4 c) {
  return __builtin_amdgcn_mfma_f32_16x16x32_bf16(a, b, c, 0, 0, 0);
}

// async global->LDS, 16B per lane; LDS dest wave-uniform base (+lane*16 HW)
__device__ __forceinline__ void gll16(uint16_t* lds, const uint16_t* g) {
  __builtin_amdgcn_global_load_lds(
      (const __attribute__((address_space(1))) uint32_t*)g,
      (__attribute__((address_space(3))) uint32_t*)lds, 16, 0, 0);
}

// Granule swizzle (BK=32 tile = [64 rows][4 granules of 8 bf16]); stored
// granule (row,s) holds global (row, kg = s ^ ((row>>1)&3)). gload_lds dest
// LINEAR; permutation in per-lane GLOBAL source. Verified: conflicts 2.1M->0.
__device__ __forceinline__ int fidx(int row, int l4) {
  return row * 4 + (l4 ^ ((row >> 1) & 3));
}

// One 64-row x 32-k tile: 256 granules -> 1 gll16 per thread.
__device__ __forceinline__ void stage64r(const uint16_t* __restrict__ src,
                                         uint16_t* lds, int tid) {
  const int wb = tid & 192;  // wave*64 granules (linear LDS dest)
  const int row = tid >> 2;
  const int kg = (tid & 3) ^ ((row >> 1) & 3);
  gll16(lds + wb * 8, src + row * UNITS + kg * 8);
}

// ---- prep (fused): blocks [0,4096): h f32->bf16; [4096,8192): R -> RT bf16 ----
__global__ __launch_bounds__(256) void prep_kernel(const float* __restrict__ h32,
                                                   uint16_t* __restrict__ hbf,
                                                   const float* __restrict__ R,
                                                   uint16_t* __restrict__ RT) {
  __shared__ float t[32][33];
  const int b = blockIdx.x;
  if (b < 4096) {
    const int i = (b * 256 + threadIdx.x) * 4;
    float4 v = *(const float4*)(h32 + i);
    ushort4 o;
    o.x = f2bf(v.x); o.y = f2bf(v.y); o.z = f2bf(v.z); o.w = f2bf(v.w);
    *(ushort4*)(hbf + i) = o;
  } else {
    const int bb = b - 4096;
    const int n0 = (bb & 127) * 32, k0 = (bb >> 7) * 32;
    const int tx = threadIdx.x & 31, ty = threadIdx.x >> 5;
#pragma unroll
    for (int i = 0; i < 4; ++i)
      t[ty + i * 8][tx] = R[(size_t)(k0 + ty + i * 8) * FOURU + n0 + tx];
    __syncthreads();
#pragma unroll
    for (int i = 0; i < 4; ++i)
      RT[(size_t)(n0 + ty + i * 8) * UNITS + k0 + tx] = f2bf(t[tx][ty + i * 8]);
  }
}

// ---- unified GEMM: BM=BN=64, BK=32, 4 waves of 32x32 (acc 2x2).
// 16 KB LDS, 6 blocks/CU (24 waves/CU): max-TLP latency hiding.
// R4-proven 2-phase loop: stage(t+1) -> consume(t) -> one barrier.
// EPI 0: s1 (z cols [0,1024), r cols [1024,2048)) -> zb(bf16) / rhb(bf16)
// EPI 1: s2: hh=tanh(+ch+b1); hn=z*h+(1-z)*hh -> h_out(f32) + hnb(bf16)
// EPI 2: s3: o =tanh(+co+b2) -> o_out(f32)
template <int EPI>
__global__ __launch_bounds__(256, 6) void gemm_kernel(
    const uint16_t* __restrict__ abf, const uint16_t* __restrict__ bt,
    const int* __restrict__ idx, const float* __restrict__ kc,
    const float* __restrict__ bz, const float* __restrict__ bias,
    const uint16_t* __restrict__ hbf, const uint16_t* __restrict__ zb_in,
    float* __restrict__ out32, uint16_t* __restrict__ outbf,
    uint16_t* __restrict__ out2bf) {
  __shared__ uint16_t sA[2][64 * 32];  // 8 KB
  __shared__ uint16_t sB[2][64 * 32];  // 8 KB
  const int tid = threadIdx.x;
  const int lane = tid & 63, wave = tid >> 6;
  const int l15 = lane & 15, l4 = lane >> 4;
  // T1 bijective XCD swizzle (nwg divisible by 8); M/BM = 64 rows always.
  const int fid = blockIdx.y * gridDim.x + blockIdx.x;
  const int qx = (gridDim.x * gridDim.y) >> 3;
  const int nid = (fid & 7) * qx + (fid >> 3);
  const int row0 = (nid & 63) * 64;
  const int col0 = (nid >> 6) * 64;
  const int wr = wave >> 1, wc = wave & 1;
  const uint16_t* pa = abf + (size_t)row0 * UNITS;
  const uint16_t* pb = bt + (size_t)col0 * UNITS;
  f32x4 acc[2][2] = {};

  stage64r(pa, sA[0], tid);
  stage64r(pb, sB[0], tid);
  __syncthreads();

  int cur = 0;
  for (int t = 0; t < 32; ++t) {
    if (t < 31) {  // issue next-tile loads before compute
      stage64r(pa + (t + 1) * 32, sA[cur ^ 1], tid);
      stage64r(pb + (t + 1) * 32, sB[cur ^ 1], tid);
    }
    const bf16x8* A8 = (const bf16x8*)sA[cur];
    const bf16x8* B8 = (const bf16x8*)sB[cur];
    bf16x8 af[2], bfr[2];
#pragma unroll
    for (int m = 0; m < 2; ++m) af[m] = A8[fidx(wr * 32 + m * 16 + l15, l4)];
#pragma unroll
    for (int n = 0; n < 2; ++n) bfr[n] = B8[fidx(wc * 32 + n * 16 + l15, l4)];
#pragma unroll
    for (int m = 0; m < 2; ++m)
#pragma unroll
      for (int n = 0; n < 2; ++n)
        acc[m][n] = mfma16x16x32(af[m], bfr[n], acc[m][n]);
    __syncthreads();  // drains gll_lds (vmcnt) + own ds_reads (lgkm)
    cur ^= 1;
  }

  const bool is_z = (col0 < UNITS);  // block-uniform (EPI 0 only)
#pragma unroll
  for (int m = 0; m < 2; ++m) {
#pragma unroll
    for (int q = 0; q < 4; ++q) {
      const int i = row0 + wr * 32 + m * 16 + l4 * 4 + q;
      const int ch = idx[i];
      const float* kcrow = kc + (size_t)ch * FOURU;
#pragma unroll
      for (int n = 0; n < 2; ++n) {
        const int jc = col0 + wc * 32 + n * 16 + l15;
        const float a = acc[m][n][q];
        if (EPI == 0) {
          if (is_z) {
            float z = fsig(a + kcrow[jc] + bz[jc]);
            outbf[(size_t)i * UNITS + jc] = f2bf(z);
          } else {
            const int j = jc - UNITS;
            const size_t ij = (size_t)i * UNITS + j;
            float r = fsig(a + kcrow[jc] + bias[j]);
            out2bf[ij] = f2bf(r * bf2f(hbf[ij]));
          }
        } else if (EPI == 1) {
          const size_t ij = (size_t)i * UNITS + jc;
          float hh = tanhf(a + kcrow[2 * UNITS + jc] + bias[UNITS + jc]);
          float z = bf2f(zb_in[ij]);
          float hv = bf2f(hbf[ij]);
          float hn = z * hv + (1.0f - z) * hh;
          out32[ij] = hn;
          outbf[ij] = f2bf(hn);
        } else {
          const size_t ij = (size_t)i * UNITS + jc;
          out32[ij] = tanhf(a + kcrow[3 * UNITS + jc] + bias[2 * UNITS + jc]);
        }
      }
    }
  }
}

extern "C" void kernel_launch(void* const* d_in, const int* in_sizes, int n_in,
                              void* d_out, int out_size, void* d_ws, size_t ws_size,
                              hipStream_t stream) {
  const int* idx = (const int*)d_in[0];
  const float* h32 = (const float*)d_in[1];
  const float* R = (const float*)d_in[2];
  const float* kc = (const float*)d_in[3];
  const float* bz = (const float*)d_in[4];
  const float* bias = (const float*)d_in[5];

  float* o_out = (float*)d_out;                  // 4M f32 (output o)
  float* h_out = o_out + (size_t)BATCH * UNITS;  // 4M f32 (output h)

  uint16_t* hbf = (uint16_t*)d_ws;               // bf16(h_tm1)   8 MB
  uint16_t* rt = hbf + (size_t)BATCH * UNITS;    // bf16(R^T)     8 MB
  uint16_t* rhb = rt + (size_t)FOURU * UNITS;    // bf16(r*h)     8 MB
  uint16_t* hnb = rhb + (size_t)BATCH * UNITS;   // bf16(h_new)   8 MB
  uint16_t* zbuf = hnb + (size_t)BATCH * UNITS;  // bf16(z)       8 MB

  prep_kernel<<<dim3(8192), 256, 0, stream>>>(h32, hbf, R, rt);

  // s1: N=2048 z|r GEMM -> grid (32,64)=2048 blocks
  gemm_kernel<0><<<dim3(32, 64), 256, 0, stream>>>(
      hbf, rt, idx, kc, bz, bias, hbf, nullptr, nullptr, zbuf, rhb);

  // s2: N=1024 -> grid (16,64)=1024 blocks
  gemm_kernel<1><<<dim3(16, 64), 256, 0, stream>>>(
      rhb, rt + (size_t)2 * UNITS * UNITS, idx, kc, bz, bias, hbf, zbuf,
      h_out, hnb, nullptr);

  // s3: N=1024 -> grid (16,64)=1024 blocks
  gemm_kernel<2><<<dim3(16, 64), 256, 0, stream>>>(
      hnb, rt + (size_t)3 * UNITS * UNITS, idx, kc, bz, bias, nullptr, nullptr,
      o_out, nullptr, nullptr);
}